// Round 4
// baseline (1095.184 us; speedup 1.0000x reference)
//
#include <hip/hip_runtime.h>

// VecLeadingZeroDetector108: X [n_rows, 108] float32 bits (exact 0.0/1.0),
// out [n_rows, 7] float32 = binary (MSB-first) index of first set bit, or
// 108 = 1101100b if the row is all zero.
//
// R3: wave-per-4-rows, ballot + dynamic readlane, no LDS, no barriers.
// 4 rows = 108 float4 = 1728 B contiguous. Two 54-lane uint4 loads per group
// (each 864 B, fully coalesced). Per lane: 4-bit nonzero nibble (~7 VALU).
// One __ballot per load -> per-row 27-bit nonzero maps live in SGPRs; the
// first-set search (ffs + readlane) runs on the scalar pipe. Lanes 0..27
// write the 28 output floats of the group contiguously. VALU ~41 us/CU vs
// memory ~137 us/CU -> memory-bound.

#define NBITS 108
#define NOUT 7
#define F4R 27

__global__ __launch_bounds__(256) void lzd108_kernel(const uint4* __restrict__ X4,
                                                     float* __restrict__ out,
                                                     int n_rows) {
    const int lane = threadIdx.x & 63;
    const long long wave    = (long long)blockIdx.x * 4 + (threadIdx.x >> 6);
    const long long nwaves  = (long long)gridDim.x * 4;
    const long long ngroups = ((long long)n_rows + 3) >> 2;   // 4 rows per group

    for (long long g = wave; g < ngroups; g += nwaves) {
        const long long row0 = g << 2;
        int rows_here = (int)(n_rows - row0);
        if (rows_here > 4) rows_here = 4;
        const int act0 = (rows_here >= 2 ? 2 : rows_here) * F4R;     // lanes for load 0
        const int act1 = (rows_here > 2 ? rows_here - 2 : 0) * F4R;  // lanes for load 1

        const uint4* base = X4 + row0 * F4R;
        unsigned m0 = 0u, m1 = 0u;
        if (lane < act0) {
            uint4 v = base[lane];
            m0 = (v.x ? 1u : 0u) | (v.y ? 2u : 0u) | (v.z ? 4u : 0u) | (v.w ? 8u : 0u);
        }
        if (lane < act1) {
            uint4 v = base[54 + lane];
            m1 = (v.x ? 1u : 0u) | (v.y ? 2u : 0u) | (v.z ? 4u : 0u) | (v.w ? 8u : 0u);
        }
        const unsigned long long nz0 = __ballot(m0 != 0u);
        const unsigned long long nz1 = __ballot(m1 != 0u);

        // All of this is wave-uniform (SGPR) work: masks, branches, ffs.
        int i0 = NBITS, i1 = NBITS, i2 = NBITS, i3 = NBITS;
        {
            const unsigned long long a = nz0 & 0x7FFFFFFull;
            if (a) { const int l = __ffsll(a) - 1;
                     const unsigned mm = __builtin_amdgcn_readlane(m0, l);
                     i0 = l * 4 + __ffs(mm) - 1; }
            const unsigned long long b = (nz0 >> 27) & 0x7FFFFFFull;
            if (b) { const int l = __ffsll(b) - 1;
                     const unsigned mm = __builtin_amdgcn_readlane(m0, l + 27);
                     i1 = l * 4 + __ffs(mm) - 1; }
            const unsigned long long c = nz1 & 0x7FFFFFFull;
            if (c) { const int l = __ffsll(c) - 1;
                     const unsigned mm = __builtin_amdgcn_readlane(m1, l);
                     i2 = l * 4 + __ffs(mm) - 1; }
            const unsigned long long d = (nz1 >> 27) & 0x7FFFFFFull;
            if (d) { const int l = __ffsll(d) - 1;
                     const unsigned mm = __builtin_amdgcn_readlane(m1, l + 27);
                     i3 = l * 4 + __ffs(mm) - 1; }
        }

        // Lanes 0..(7*rows_here-1) store the group's outputs contiguously.
        if (lane < NOUT * rows_here) {
            const int r = lane / NOUT;          // 0..3
            const int j = lane - r * NOUT;      // 0..6 (MSB-first position)
            const int id01 = (r == 0) ? i0 : i1;
            const int id23 = (r == 2) ? i2 : i3;
            const int id = (r < 2) ? id01 : id23;
            out[row0 * NOUT + lane] = (float)((id >> (6 - j)) & 1);
        }
    }
}

extern "C" void kernel_launch(void* const* d_in, const int* in_sizes, int n_in,
                              void* d_out, int out_size, void* d_ws, size_t ws_size,
                              hipStream_t stream) {
    const uint4* X4 = (const uint4*)d_in[0];
    float* out = (float*)d_out;
    const int n_rows = in_sizes[0] / NBITS;
    const int grid = 4096;   // 16384 waves; ~30 groups each; 8 blocks/CU resident
    lzd108_kernel<<<grid, 256, 0, stream>>>(X4, out, n_rows);
}

// Round 5
// 1057.053 us; speedup vs baseline: 1.0361x; 1.0361x over previous
//
#include <hip/hip_runtime.h>

// VecLeadingZeroDetector108: X [n_rows, 108] float32 bits (exact 0.0/1.0),
// out [n_rows, 7] float32 = binary (MSB-first) index of first set bit, or
// 108 = 1101100b if the row is all zero.
//
// R4: two-stage early-exit, wave-per-8-rows, ballot + readlane, no LDS.
// Stage 1: one 64-lane uint4 load = f4 0..7 (bits 0..31) of 8 rows; ballot
// resolves rows with first-set < 32 (p=0.623 at bit density 0.03). Stage 2:
// unresolved rows 3-at-a-time, 57 lanes load f4 8..26 (bits 32..107), one
// ballot resolves. Expected fetch ~60% of full read — bytes are the lever:
// R0's early exit beat all coalesced full readers. Results packed 7b/row in
// a u64; lanes 0..13 store the 56 output floats as contiguous float4s.

#define NBITS 108
#define NOUT 7
#define F4R 27

__global__ __launch_bounds__(256) void lzd108_kernel(const uint4* __restrict__ X4,
                                                     float* __restrict__ out,
                                                     int n_rows) {
    const int lane = threadIdx.x & 63;
    const long long wave    = (long long)blockIdx.x * 4 + (threadIdx.x >> 6);
    const long long nwaves  = (long long)gridDim.x * 4;
    const long long ngroups = ((long long)n_rows + 7) >> 3;   // 8 rows per group

    // lane mappings
    const int r8  = lane >> 3;           // stage-1 row slot 0..7
    const int k8  = lane & 7;            // stage-1 f4 index 0..7
    const int rr  = lane / 19;           // stage-2 row slot 0..3 (lanes 57..63 -> 3)
    const int k19 = lane - rr * 19;      // stage-2 f4 index 0..18

    for (long long g = wave; g < ngroups; g += nwaves) {
        const long long row0 = g << 3;
        int rows_here = (int)(n_rows - row0);
        if (rows_here > 8) rows_here = 8;
        const uint4* base = X4 + row0 * F4R;

        if (rows_here == 8) {
            // ---- Stage 1: bits 0..31 of all 8 rows in one load ----
            uint4 v = base[r8 * F4R + k8];
            unsigned m = (v.x ? 1u : 0u) | (v.y ? 2u : 0u)
                       | (v.z ? 4u : 0u) | (v.w ? 8u : 0u);
            const unsigned long long nz = __ballot(m != 0u);

            unsigned long long packed = 0;   // 7 bits per row, rows 0..7
            unsigned long long list = 0;     // 4-bit ids of unresolved rows
            int nu = 0;
            #pragma unroll
            for (int r = 0; r < 8; ++r) {
                const unsigned g8 = (unsigned)(nz >> (8 * r)) & 0xFFu;
                if (g8) {
                    const int l = __ffs(g8) - 1;
                    const unsigned mm = __builtin_amdgcn_readlane(m, 8 * r + l);
                    const unsigned id = 4u * l + __ffs(mm) - 1u;
                    packed |= (unsigned long long)id << (7 * r);
                } else {
                    list |= (unsigned long long)r << (4 * nu);
                    ++nu;
                }
            }

            // ---- Stage 2: bits 32..107 for unresolved rows, 3 at a time ----
            int done = 0;
            while (done < nu) {
                int take = nu - done;
                if (take > 3) take = 3;
                unsigned m2 = 0u;
                const bool active = (lane < 19 * take);
                if (active) {
                    const unsigned rid =
                        (unsigned)((list >> (4 * (done + rr))) & 0xFull);
                    uint4 v2 = base[rid * F4R + 8 + k19];
                    m2 = (v2.x ? 1u : 0u) | (v2.y ? 2u : 0u)
                       | (v2.z ? 4u : 0u) | (v2.w ? 8u : 0u);
                }
                const unsigned long long nz2 = __ballot(m2 != 0u);
                for (int s = 0; s < take; ++s) {     // wave-uniform, <=3
                    const unsigned g19 = (unsigned)(nz2 >> (19 * s)) & 0x7FFFFu;
                    const int r = (int)((list >> (4 * (done + s))) & 0xF);
                    unsigned id;
                    if (g19) {
                        const int l = __ffs(g19) - 1;
                        const unsigned mm = __builtin_amdgcn_readlane(m2, 19 * s + l);
                        id = 32u + 4u * l + __ffs(mm) - 1u;
                    } else {
                        id = NBITS;                  // all-zero row
                    }
                    packed |= (unsigned long long)id << (7 * r);
                }
                done += take;
            }

            // ---- Writeback: 8 rows x 7 = 56 floats = 14 float4, contiguous ----
            if (lane < 14) {
                float4 o;
                float vals[4];
                #pragma unroll
                for (int c = 0; c < 4; ++c) {
                    const int j = 4 * lane + c;          // 0..55
                    const int row = (j * 9363) >> 16;    // j / 7 for j < 56
                    const int bit = j - row * NOUT;      // 0..6, MSB-first
                    const unsigned id = (unsigned)((packed >> (7 * row)) & 0x7Fu);
                    vals[c] = (float)((id >> (6 - bit)) & 1u);
                }
                o.x = vals[0]; o.y = vals[1]; o.z = vals[2]; o.w = vals[3];
                reinterpret_cast<float4*>(out + row0 * NOUT)[lane] = o;
            }
        } else {
            // Tail group (at most one per grid pass): scalar per-row.
            if (lane < rows_here) {
                const unsigned* r = reinterpret_cast<const unsigned*>(base)
                                  + (long long)lane * NBITS;
                int id = NBITS;
                for (int j = 0; j < NBITS; ++j) {
                    if (r[j] != 0u) { id = j; break; }
                }
                float* o = out + (row0 + lane) * NOUT;
                #pragma unroll
                for (int b = 0; b < NOUT; ++b)
                    o[b] = (float)((id >> (6 - b)) & 1);
            }
        }
    }
}

extern "C" void kernel_launch(void* const* d_in, const int* in_sizes, int n_in,
                              void* d_out, int out_size, void* d_ws, size_t ws_size,
                              hipStream_t stream) {
    const uint4* X4 = (const uint4*)d_in[0];
    float* out = (float*)d_out;
    const int n_rows = in_sizes[0] / NBITS;
    const int grid = 4096;   // 16384 waves, ~15 groups each
    lzd108_kernel<<<grid, 256, 0, stream>>>(X4, out, n_rows);
}